// Round 1
// baseline (170.104 us; speedup 1.0000x reference)
//
#include <hip/hip_runtime.h>
#include <hip/hip_bf16.h>
#include <math.h>

typedef __bf16 bf16;
typedef __attribute__((ext_vector_type(8))) __bf16 bf16x8;
typedef __attribute__((ext_vector_type(4))) __bf16 bf16x4;
typedef __attribute__((ext_vector_type(4))) short s16x4;
typedef __attribute__((ext_vector_type(4))) float f32x4;

#define T_SEQ 2048

// ---------------- fp32 -> bf16 elementwise convert (x) ----------------
__global__ void convert_kernel(const float* __restrict__ x, bf16* __restrict__ xb, int n4)
{
    int i = blockIdx.x * blockDim.x + threadIdx.x;
    int stride = gridDim.x * blockDim.x;
    for (; i < n4; i += stride) {
        f32x4 v = ((const f32x4*)x)[i];
        bf16x4 o;
        o[0] = (bf16)v[0]; o[1] = (bf16)v[1]; o[2] = (bf16)v[2]; o[3] = (bf16)v[3];
        ((bf16x4*)xb)[i] = o;
    }
}

// ---------------- tiled transpose + convert: W[K][N] f32 -> Wt[N][K] bf16 ----------------
__global__ __launch_bounds__(256) void transpose_conv_kernel(
    const float* __restrict__ W, bf16* __restrict__ Wt, int K, int N)
{
    __shared__ float tile[32][33];
    int tx = threadIdx.x & 31, ty = threadIdx.x >> 5;       // ty 0..7
    int n0 = blockIdx.x * 32, k0 = blockIdx.y * 32;
#pragma unroll
    for (int j = 0; j < 4; ++j)
        tile[ty + j * 8][tx] = W[(size_t)(k0 + ty + j * 8) * N + n0 + tx];
    __syncthreads();
#pragma unroll
    for (int j = 0; j < 4; ++j)
        Wt[(size_t)(n0 + ty + j * 8) * K + k0 + tx] = (bf16)tile[tx][ty + j * 8];
}

// ---------------- GEMM: C[M][N] = A[M][K] * Bt[N][K]^T + bias ----------------
// 128x128 tile, BK=64, 4 waves (2x2), each wave 64x64 via 4x4 16x16x32 frags.
template<int OUT_BF16>
__global__ __launch_bounds__(256) void gemm_bias_kernel(
    const bf16* __restrict__ A, const bf16* __restrict__ Bt,
    const float* __restrict__ bias, void* __restrict__ Cout,
    int M, int N, int K)
{
    __shared__ bf16 As[128][72];
    __shared__ bf16 Bs[128][72];
    const int tid = threadIdx.x;
    const int lane = tid & 63, wid = tid >> 6;
    const int wm = wid >> 1, wn = wid & 1;
    const int m0 = blockIdx.y * 128, n0 = blockIdx.x * 128;
    const int l15 = lane & 15, l4 = lane >> 4;

    f32x4 acc[4][4] = {};

    for (int kt = 0; kt < K; kt += 64) {
        // stage A and B tiles: 128 rows x 64 cols bf16 = 1024 chunks of 16B each
#pragma unroll
        for (int it = 0; it < 4; ++it) {
            int ch = tid + it * 256;
            int r = ch >> 3, c = (ch & 7) * 8;
            *(bf16x8*)&As[r][c] = *(const bf16x8*)&A[(size_t)(m0 + r) * K + kt + c];
            *(bf16x8*)&Bs[r][c] = *(const bf16x8*)&Bt[(size_t)(n0 + r) * K + kt + c];
        }
        __syncthreads();
#pragma unroll
        for (int kk = 0; kk < 2; ++kk) {
            bf16x8 af[4], bfr[4];
#pragma unroll
            for (int mi = 0; mi < 4; ++mi)
                af[mi] = *(const bf16x8*)&As[wm * 64 + mi * 16 + l15][kk * 32 + l4 * 8];
#pragma unroll
            for (int ni = 0; ni < 4; ++ni)
                bfr[ni] = *(const bf16x8*)&Bs[wn * 64 + ni * 16 + l15][kk * 32 + l4 * 8];
#pragma unroll
            for (int mi = 0; mi < 4; ++mi)
#pragma unroll
                for (int ni = 0; ni < 4; ++ni)
                    acc[mi][ni] = __builtin_amdgcn_mfma_f32_16x16x32_bf16(
                        af[mi], bfr[ni], acc[mi][ni], 0, 0, 0);
        }
        __syncthreads();
    }
    // epilogue: C[row][col] = acc + bias[col]
#pragma unroll
    for (int mi = 0; mi < 4; ++mi) {
#pragma unroll
        for (int ni = 0; ni < 4; ++ni) {
            int col = n0 + wn * 64 + ni * 16 + l15;
            float bv = bias[col];
#pragma unroll
            for (int r = 0; r < 4; ++r) {
                int row = m0 + wm * 64 + mi * 16 + l4 * 4 + r;
                float v = acc[mi][ni][r] + bv;
                if (OUT_BF16) ((bf16*)Cout)[(size_t)row * N + col] = (bf16)v;
                else          ((float*)Cout)[(size_t)row * N + col] = v;
            }
        }
    }
}

// ---------------- causal flash attention ----------------
// qkv: [B*T, 3072] bf16 (q|k|v concat). attb: [B*T, 1024] bf16 (heads concat).
// Block: 4 waves x 32 q-rows = 128 q-rows. KV tiles of 64 staged in LDS.
// S^T = mfma(K, Q)  => S'[k][q], C-layout k=(l>>4)*4+r, q=l&15
// PV: out^T = mfma_16x16x16(V^T, P')  -- P' register layout matches B-operand exactly.
__global__ __launch_bounds__(256) void attn_kernel(
    const bf16* __restrict__ qkv, bf16* __restrict__ attb)
{
    __shared__ bf16 Ks[64][72];
    __shared__ bf16 Vs[64][72];
    const int tid = threadIdx.x, lane = tid & 63, wid = tid >> 6;
    const int bh = blockIdx.y, b = bh >> 4, h = bh & 15;
    const int qb = blockIdx.x * 128;
    const int q0 = qb + wid * 32;
    const int l15 = lane & 15, l4 = lane >> 4;
    const size_t base = (size_t)b * T_SEQ * 3072;
    const int qoffc = h * 64, koff = 1024 + h * 64, voff = 2048 + h * 64;

    // hoist Q fragments (B-operand layout: q=l&15, d=(l>>4)*8+i)
    bf16x8 Qf[2][2];
#pragma unroll
    for (int qf = 0; qf < 2; ++qf)
#pragma unroll
        for (int dh = 0; dh < 2; ++dh)
            Qf[qf][dh] = *(const bf16x8*)&qkv[base + (size_t)(q0 + qf * 16 + l15) * 3072
                                             + qoffc + dh * 32 + l4 * 8];

    f32x4 Oacc[4][2] = {};
    float m_run[2] = { -1e30f, -1e30f };
    float l_run[2] = { 0.f, 0.f };

    const int nt = qb / 64 + 2;   // covers k up to qb+128 for the whole block
    for (int t = 0; t < nt; ++t) {
        const int k0g = t * 64;
        __syncthreads();
        // stage K tile: 64 rows x 64 cols, 512 x 16B chunks
#pragma unroll
        for (int it = 0; it < 2; ++it) {
            int ch = tid + it * 256;
            int r = ch >> 3, c = (ch & 7) * 8;
            *(bf16x8*)&Ks[r][c] = *(const bf16x8*)&qkv[base + (size_t)(k0g + r) * 3072 + koff + c];
        }
        // stage V transposed: Vs[d][k]
        {
            int kk = tid >> 2, dbase = (tid & 3) * 16;
            const bf16* src = &qkv[base + (size_t)(k0g + kk) * 3072 + voff + dbase];
            bf16x8 v0 = *(const bf16x8*)src;
            bf16x8 v1 = *(const bf16x8*)(src + 8);
#pragma unroll
            for (int j = 0; j < 8; ++j) {
                Vs[dbase + j][kk] = v0[j];
                Vs[dbase + 8 + j][kk] = v1[j];
            }
        }
        __syncthreads();
        if (k0g > q0 + 31) continue;   // this wave fully masked for this tile

        // S^T accumulate over d=64 (2 halves)
        f32x4 S[4][2] = {};
#pragma unroll
        for (int dh = 0; dh < 2; ++dh) {
#pragma unroll
            for (int kf = 0; kf < 4; ++kf) {
                bf16x8 kfr = *(const bf16x8*)&Ks[kf * 16 + l15][dh * 32 + l4 * 8];
#pragma unroll
                for (int qf = 0; qf < 2; ++qf)
                    S[kf][qf] = __builtin_amdgcn_mfma_f32_16x16x32_bf16(
                        kfr, Qf[qf][dh], S[kf][qf], 0, 0, 0);
            }
        }
        // scale + causal mask + online softmax (per q column = per lane&15, per qf)
#pragma unroll
        for (int qf = 0; qf < 2; ++qf) {
            const int q = q0 + qf * 16 + l15;
            float pmax = -1e30f;
#pragma unroll
            for (int kf = 0; kf < 4; ++kf)
#pragma unroll
                for (int r = 0; r < 4; ++r) {
                    int kidx = k0g + kf * 16 + l4 * 4 + r;
                    float s = S[kf][qf][r] * 0.125f;
                    s = (kidx <= q) ? s : -1e30f;
                    S[kf][qf][r] = s;
                    pmax = fmaxf(pmax, s);
                }
            pmax = fmaxf(pmax, __shfl_xor(pmax, 16));
            pmax = fmaxf(pmax, __shfl_xor(pmax, 32));
            float mnew = fmaxf(m_run[qf], pmax);
            float alpha = __expf(m_run[qf] - mnew);
            m_run[qf] = mnew;
            float lsum = 0.f;
#pragma unroll
            for (int kf = 0; kf < 4; ++kf)
#pragma unroll
                for (int r = 0; r < 4; ++r) {
                    float p = __expf(S[kf][qf][r] - mnew);
                    S[kf][qf][r] = p;
                    lsum += p;
                }
            lsum += __shfl_xor(lsum, 16);
            lsum += __shfl_xor(lsum, 32);
            l_run[qf] = l_run[qf] * alpha + lsum;
#pragma unroll
            for (int df = 0; df < 4; ++df)
                Oacc[df][qf] *= alpha;
        }
        // P -> bf16 fragments (already in 16x16x16 B-operand layout)
        s16x4 Pb[4][2];
#pragma unroll
        for (int kf = 0; kf < 4; ++kf)
#pragma unroll
            for (int qf = 0; qf < 2; ++qf)
#pragma unroll
                for (int r = 0; r < 4; ++r) {
                    bf16 pb = (bf16)S[kf][qf][r];
                    Pb[kf][qf][r] = __builtin_bit_cast(short, pb);
                }
        // PV: out^T += V^T * P'   (16x16x16, K=16 per kf)
#pragma unroll
        for (int kf = 0; kf < 4; ++kf) {
#pragma unroll
            for (int df = 0; df < 4; ++df) {
                bf16x4 av = *(const bf16x4*)&Vs[df * 16 + l15][kf * 16 + l4 * 4];
                s16x4 avs = __builtin_bit_cast(s16x4, av);
#pragma unroll
                for (int qf = 0; qf < 2; ++qf)
                    Oacc[df][qf] = __builtin_amdgcn_mfma_f32_16x16x16bf16_1k(
                        avs, Pb[kf][qf], Oacc[df][qf], 0, 0, 0);
            }
        }
    }
    // write: attb[(b*T+q)*1024 + h*64 + d] = Oacc^T / l
#pragma unroll
    for (int qf = 0; qf < 2; ++qf) {
        float inv = 1.f / l_run[qf];
        int q = q0 + qf * 16 + l15;
#pragma unroll
        for (int df = 0; df < 4; ++df)
#pragma unroll
            for (int r = 0; r < 4; ++r) {
                int d = df * 16 + l4 * 4 + r;
                attb[((size_t)b * T_SEQ + q) * 1024 + qoffc + d] = (bf16)(Oacc[df][qf][r] * inv);
            }
    }
}

// ---------------- launcher ----------------
extern "C" void kernel_launch(void* const* d_in, const int* in_sizes, int n_in,
                              void* d_out, int out_size, void* d_ws, size_t ws_size,
                              hipStream_t stream)
{
    const float* x    = (const float*)d_in[0];   // [2,2048,1024]
    const float* Wqkv = (const float*)d_in[1];   // [1024,3072]
    const float* bqkv = (const float*)d_in[2];   // [3072]
    const float* Wout = (const float*)d_in[3];   // [1024,1024]
    const float* bout = (const float*)d_in[4];   // [1024]
    float* out = (float*)d_out;                  // [2,2048,1024] f32

    char* ws = (char*)d_ws;
    bf16* xb    = (bf16*)(ws);                    // 4096*1024   (8 MB)
    bf16* Wqkvt = (bf16*)(ws + (8ull  << 20));    // 3072*1024   (6 MB)
    bf16* Woutt = (bf16*)(ws + (14ull << 20));    // 1024*1024   (2 MB)
    bf16* qkvb  = (bf16*)(ws + (16ull << 20));    // 4096*3072   (24 MB)
    bf16* attb  = (bf16*)(ws + (40ull << 20));    // 4096*1024   (8 MB)

    convert_kernel<<<dim3(2048), dim3(256), 0, stream>>>(x, xb, (4096 * 1024) / 4);
    transpose_conv_kernel<<<dim3(96, 32), dim3(256), 0, stream>>>(Wqkv, Wqkvt, 1024, 3072);
    transpose_conv_kernel<<<dim3(32, 32), dim3(256), 0, stream>>>(Wout, Woutt, 1024, 1024);
    gemm_bias_kernel<1><<<dim3(24, 32), dim3(256), 0, stream>>>(
        xb, Wqkvt, bqkv, (void*)qkvb, 4096, 3072, 1024);
    attn_kernel<<<dim3(16, 32), dim3(256), 0, stream>>>(qkvb, attb);
    gemm_bias_kernel<0><<<dim3(8, 32), dim3(256), 0, stream>>>(
        attb, Woutt, bout, (void*)out, 4096, 1024, 1024);
}

// Round 2
// 134.703 us; speedup vs baseline: 1.2628x; 1.2628x over previous
//
#include <hip/hip_runtime.h>
#include <hip/hip_bf16.h>
#include <math.h>

typedef __bf16 bf16;
typedef __attribute__((ext_vector_type(8))) __bf16 bf16x8;
typedef __attribute__((ext_vector_type(4))) __bf16 bf16x4;
typedef __attribute__((ext_vector_type(4))) short s16x4;
typedef __attribute__((ext_vector_type(4))) float f32x4;

#define T_SEQ 2048

static __device__ __forceinline__ float fast_exp2(float x) {
#if __has_builtin(__builtin_amdgcn_exp2f)
    return __builtin_amdgcn_exp2f(x);
#else
    return __expf(x * 0.69314718f);
#endif
}

// ---------------- fp32 -> bf16 elementwise convert (x) ----------------
__global__ void convert_kernel(const float* __restrict__ x, bf16* __restrict__ xb, int n4)
{
    int i = blockIdx.x * blockDim.x + threadIdx.x;
    int stride = gridDim.x * blockDim.x;
    for (; i < n4; i += stride) {
        f32x4 v = ((const f32x4*)x)[i];
        bf16x4 o;
        o[0] = (bf16)v[0]; o[1] = (bf16)v[1]; o[2] = (bf16)v[2]; o[3] = (bf16)v[3];
        ((bf16x4*)xb)[i] = o;
    }
}

// ---------------- tiled transpose + convert: W[K][N] f32 -> Wt[N][K] bf16 ----------------
__global__ __launch_bounds__(256) void transpose_conv_kernel(
    const float* __restrict__ W, bf16* __restrict__ Wt, int K, int N)
{
    __shared__ float tile[32][33];
    int tx = threadIdx.x & 31, ty = threadIdx.x >> 5;       // ty 0..7
    int n0 = blockIdx.x * 32, k0 = blockIdx.y * 32;
#pragma unroll
    for (int j = 0; j < 4; ++j)
        tile[ty + j * 8][tx] = W[(size_t)(k0 + ty + j * 8) * N + n0 + tx];
    __syncthreads();
#pragma unroll
    for (int j = 0; j < 4; ++j)
        Wt[(size_t)(n0 + ty + j * 8) * K + k0 + tx] = (bf16)tile[tx][ty + j * 8];
}

// ---------------- V pre-transpose: Vt[bh][d][t] = qkv[b][t][2048 + h*64 + d] ----------------
__global__ __launch_bounds__(256) void vtrans_kernel(
    const bf16* __restrict__ qkv, bf16* __restrict__ Vt)
{
    __shared__ bf16 tile[64][72];
    const int tid = threadIdx.x;
    const int bh = blockIdx.y, b = bh >> 4, h = bh & 15;
    const int t0 = blockIdx.x * 64;
    const size_t base = (size_t)b * T_SEQ * 3072 + 2048 + h * 64;
    const int r = tid >> 3, c = (tid & 7) * 8;
    *(bf16x8*)&tile[r][c]      = *(const bf16x8*)&qkv[base + (size_t)(t0 + r) * 3072 + c];
    *(bf16x8*)&tile[r + 32][c] = *(const bf16x8*)&qkv[base + (size_t)(t0 + r + 32) * 3072 + c];
    __syncthreads();
    bf16x8 o0, o1;
#pragma unroll
    for (int j = 0; j < 8; ++j) { o0[j] = tile[c + j][r]; o1[j] = tile[c + j][r + 32]; }
    *(bf16x8*)&Vt[((size_t)bh * 64 + r) * T_SEQ + t0 + c] = o0;
    *(bf16x8*)&Vt[((size_t)bh * 64 + r + 32) * T_SEQ + t0 + c] = o1;
}

// ---------------- GEMM: C[M][N] = A[M][K] * Bt[N][K]^T + bias ----------------
template<int OUT_BF16>
__global__ __launch_bounds__(256) void gemm_bias_kernel(
    const bf16* __restrict__ A, const bf16* __restrict__ Bt,
    const float* __restrict__ bias, void* __restrict__ Cout,
    int M, int N, int K)
{
    __shared__ bf16 As[128][72];
    __shared__ bf16 Bs[128][72];
    const int tid = threadIdx.x;
    const int lane = tid & 63, wid = tid >> 6;
    const int wm = wid >> 1, wn = wid & 1;
    const int m0 = blockIdx.y * 128, n0 = blockIdx.x * 128;
    const int l15 = lane & 15, l4 = lane >> 4;

    f32x4 acc[4][4] = {};

    for (int kt = 0; kt < K; kt += 64) {
#pragma unroll
        for (int it = 0; it < 4; ++it) {
            int ch = tid + it * 256;
            int r = ch >> 3, c = (ch & 7) * 8;
            *(bf16x8*)&As[r][c] = *(const bf16x8*)&A[(size_t)(m0 + r) * K + kt + c];
            *(bf16x8*)&Bs[r][c] = *(const bf16x8*)&Bt[(size_t)(n0 + r) * K + kt + c];
        }
        __syncthreads();
#pragma unroll
        for (int kk = 0; kk < 2; ++kk) {
            bf16x8 af[4], bfr[4];
#pragma unroll
            for (int mi = 0; mi < 4; ++mi)
                af[mi] = *(const bf16x8*)&As[wm * 64 + mi * 16 + l15][kk * 32 + l4 * 8];
#pragma unroll
            for (int ni = 0; ni < 4; ++ni)
                bfr[ni] = *(const bf16x8*)&Bs[wn * 64 + ni * 16 + l15][kk * 32 + l4 * 8];
#pragma unroll
            for (int mi = 0; mi < 4; ++mi)
#pragma unroll
                for (int ni = 0; ni < 4; ++ni)
                    acc[mi][ni] = __builtin_amdgcn_mfma_f32_16x16x32_bf16(
                        af[mi], bfr[ni], acc[mi][ni], 0, 0, 0);
        }
        __syncthreads();
    }
#pragma unroll
    for (int mi = 0; mi < 4; ++mi) {
#pragma unroll
        for (int ni = 0; ni < 4; ++ni) {
            int col = n0 + wn * 64 + ni * 16 + l15;
            float bv = bias[col];
#pragma unroll
            for (int r = 0; r < 4; ++r) {
                int row = m0 + wm * 64 + mi * 16 + l4 * 4 + r;
                float v = acc[mi][ni][r] + bv;
                if (OUT_BF16) ((bf16*)Cout)[(size_t)row * N + col] = (bf16)v;
                else          ((float*)Cout)[(size_t)row * N + col] = v;
            }
        }
    }
}

// ---------------- causal flash attention (balanced fold, 16-row strips) ----------------
// qkv: [B*T, 3072] bf16. Vt: [bh][64][T] bf16 (V transposed). attb: [B*T, 1024] bf16.
// grid (16, 32): blockIdx.x = fold pair fp -> q-tiles fp and 31-fp (64 rows each),
// processed sequentially; every block does exactly 33 k-tile iterations.
// 4 waves x 16 q-rows. S^T = mfma(K, Q); PV: out^T = mfma_16x16x16(V^T, P).
__global__ __launch_bounds__(256) void attn_kernel(
    const bf16* __restrict__ qkv, const bf16* __restrict__ Vt, bf16* __restrict__ attb)
{
    __shared__ bf16 Ks[64][72];
    __shared__ bf16 Vs[64][72];
    const int tid = threadIdx.x, lane = tid & 63, wid = tid >> 6;
    const int bh = blockIdx.y, b = bh >> 4, h = bh & 15;
    const int fp = blockIdx.x;
    const int l15 = lane & 15, l4 = lane >> 4;
    const size_t base = (size_t)b * T_SEQ * 3072;
    const int koff = 1024 + h * 64;
    const size_t vtb = (size_t)bh * 64 * T_SEQ;
    const int sr = tid >> 3, sc = (tid & 7) * 8;

    for (int pass = 0; pass < 2; ++pass) {
        const int iq = pass ? 31 - fp : fp;       // q-tile index, 64 rows
        const int q0 = iq * 64 + wid * 16;
        const int nt = iq + 1;

        bf16x8 Qf[2];
#pragma unroll
        for (int dh = 0; dh < 2; ++dh)
            Qf[dh] = *(const bf16x8*)&qkv[base + (size_t)(q0 + l15) * 3072 + h * 64 + dh * 32 + l4 * 8];

        f32x4 Oacc[4] = {};
        float m_run = -1e30f, l_run = 0.f;

        // prologue: prefetch tile 0 into regs
        bf16x8 kreg0 = *(const bf16x8*)&qkv[base + (size_t)sr * 3072 + koff + sc];
        bf16x8 kreg1 = *(const bf16x8*)&qkv[base + (size_t)(sr + 32) * 3072 + koff + sc];
        bf16x8 vreg0 = *(const bf16x8*)&Vt[vtb + (size_t)sr * T_SEQ + sc];
        bf16x8 vreg1 = *(const bf16x8*)&Vt[vtb + (size_t)(sr + 32) * T_SEQ + sc];

        for (int t = 0; t < nt; ++t) {
            __syncthreads();                       // all waves done reading prev tile
            *(bf16x8*)&Ks[sr][sc]      = kreg0;
            *(bf16x8*)&Ks[sr + 32][sc] = kreg1;
            *(bf16x8*)&Vs[sr][sc]      = vreg0;
            *(bf16x8*)&Vs[sr + 32][sc] = vreg1;
            __syncthreads();                       // LDS ready
            if (t + 1 < nt) {                      // prefetch next tile (hides L2 latency)
                const int k1 = (t + 1) * 64;
                kreg0 = *(const bf16x8*)&qkv[base + (size_t)(k1 + sr) * 3072 + koff + sc];
                kreg1 = *(const bf16x8*)&qkv[base + (size_t)(k1 + sr + 32) * 3072 + koff + sc];
                vreg0 = *(const bf16x8*)&Vt[vtb + (size_t)sr * T_SEQ + k1 + sc];
                vreg1 = *(const bf16x8*)&Vt[vtb + (size_t)(sr + 32) * T_SEQ + k1 + sc];
            }
            // S^T = K . Q  (raw, unscaled)
            f32x4 S[4] = {};
#pragma unroll
            for (int dh = 0; dh < 2; ++dh)
#pragma unroll
                for (int kf = 0; kf < 4; ++kf) {
                    bf16x8 kfr = *(const bf16x8*)&Ks[kf * 16 + l15][dh * 32 + l4 * 8];
                    S[kf] = __builtin_amdgcn_mfma_f32_16x16x32_bf16(kfr, Qf[dh], S[kf], 0, 0, 0);
                }
            // max (raw domain); mask only the diagonal tile (t == nt-1, uniform)
            float pmax = -3.0e38f;
            if (t == nt - 1) {
                const int qq = wid * 16 + l15;
#pragma unroll
                for (int kf = 0; kf < 4; ++kf)
#pragma unroll
                    for (int r = 0; r < 4; ++r) {
                        if (kf * 16 + l4 * 4 + r > qq) S[kf][r] = -3.0e38f;
                        pmax = fmaxf(pmax, S[kf][r]);
                    }
            } else {
#pragma unroll
                for (int kf = 0; kf < 4; ++kf)
#pragma unroll
                    for (int r = 0; r < 4; ++r) pmax = fmaxf(pmax, S[kf][r]);
            }
            pmax = fmaxf(pmax, __shfl_xor(pmax, 16));
            pmax = fmaxf(pmax, __shfl_xor(pmax, 32));
            // defer-rescale (T13): raw-domain threshold 64 == 8 in score domain
            if (!__all(pmax - m_run <= 64.f)) {
                float mnew = fmaxf(m_run, pmax);
                float alpha = fast_exp2((m_run - mnew) * 0.18033688f);
                m_run = mnew;
                l_run *= alpha;
#pragma unroll
                for (int df = 0; df < 4; ++df) Oacc[df] *= alpha;
            }
            // P = exp2((S - m) * (0.125*log2e)), pack to bf16
            float lsum = 0.f;
            s16x4 Pb[4];
#pragma unroll
            for (int kf = 0; kf < 4; ++kf)
#pragma unroll
                for (int r = 0; r < 4; ++r) {
                    float p = fast_exp2((S[kf][r] - m_run) * 0.18033688f);
                    lsum += p;
                    Pb[kf][r] = __builtin_bit_cast(short, (bf16)p);
                }
            lsum += __shfl_xor(lsum, 16);
            lsum += __shfl_xor(lsum, 32);
            l_run += lsum;
            // out^T += V^T * P
#pragma unroll
            for (int kf = 0; kf < 4; ++kf)
#pragma unroll
                for (int df = 0; df < 4; ++df) {
                    bf16x4 av = *(const bf16x4*)&Vs[df * 16 + l15][kf * 16 + l4 * 4];
                    Oacc[df] = __builtin_amdgcn_mfma_f32_16x16x16bf16_1k(
                        __builtin_bit_cast(s16x4, av), Pb[kf], Oacc[df], 0, 0, 0);
                }
        }
        // epilogue: attb[q][h*64+d] = O^T / l   (q = l15 column, matches l_run lane)
        float inv = 1.f / l_run;
        const int qrow = q0 + l15;
#pragma unroll
        for (int df = 0; df < 4; ++df) {
            bf16x4 o;
#pragma unroll
            for (int r = 0; r < 4; ++r) o[r] = (bf16)(Oacc[df][r] * inv);
            *(bf16x4*)&attb[((size_t)b * T_SEQ + qrow) * 1024 + h * 64 + df * 16 + l4 * 4] = o;
        }
    }
}

// ---------------- launcher ----------------
extern "C" void kernel_launch(void* const* d_in, const int* in_sizes, int n_in,
                              void* d_out, int out_size, void* d_ws, size_t ws_size,
                              hipStream_t stream)
{
    const float* x    = (const float*)d_in[0];   // [2,2048,1024]
    const float* Wqkv = (const float*)d_in[1];   // [1024,3072]
    const float* bqkv = (const float*)d_in[2];   // [3072]
    const float* Wout = (const float*)d_in[3];   // [1024,1024]
    const float* bout = (const float*)d_in[4];   // [1024]
    float* out = (float*)d_out;                  // [2,2048,1024] f32

    char* ws = (char*)d_ws;
    bf16* xb    = (bf16*)(ws);                    // 8 MB (dead after gemm1)
    bf16* Vt    = (bf16*)(ws);                    // 8 MB, reuses xb region
    bf16* Wqkvt = (bf16*)(ws + (8ull  << 20));    // 6 MB
    bf16* Woutt = (bf16*)(ws + (14ull << 20));    // 2 MB
    bf16* qkvb  = (bf16*)(ws + (16ull << 20));    // 24 MB
    bf16* attb  = (bf16*)(ws + (40ull << 20));    // 8 MB

    convert_kernel<<<dim3(2048), dim3(256), 0, stream>>>(x, xb, (4096 * 1024) / 4);
    transpose_conv_kernel<<<dim3(96, 32), dim3(256), 0, stream>>>(Wqkv, Wqkvt, 1024, 3072);
    transpose_conv_kernel<<<dim3(32, 32), dim3(256), 0, stream>>>(Wout, Woutt, 1024, 1024);
    gemm_bias_kernel<1><<<dim3(24, 32), dim3(256), 0, stream>>>(
        xb, Wqkvt, bqkv, (void*)qkvb, 4096, 3072, 1024);
    vtrans_kernel<<<dim3(32, 32), dim3(256), 0, stream>>>(qkvb, Vt);
    attn_kernel<<<dim3(16, 32), dim3(256), 0, stream>>>(qkvb, Vt, attb);
    gemm_bias_kernel<0><<<dim3(8, 32), dim3(256), 0, stream>>>(
        attb, Woutt, bout, (void*)out, 4096, 1024, 1024);
}